// Round 8
// baseline (837.123 us; speedup 1.0000x reference)
//
#include <hip/hip_runtime.h>

#define DEV __device__ __forceinline__

typedef float f32x4 __attribute__((ext_vector_type(4)));
typedef short s16x8 __attribute__((ext_vector_type(8)));
typedef unsigned short u16;
typedef u16 u16x4 __attribute__((ext_vector_type(4)));
typedef u16 u16x8 __attribute__((ext_vector_type(8)));
typedef unsigned int u32x4 __attribute__((ext_vector_type(4)));

constexpr int Bb = 16, Tt = 64, Ss = 128, Dd = 512, Vv = 32000, FD = 2048;

DEV u16 f2bf(float x) {                       // RNE f32 -> bf16
  unsigned u = __builtin_bit_cast(unsigned, x);
  u = u + 0x7fffu + ((u >> 16) & 1u);
  return (u16)(u >> 16);
}
DEV float bf2f(u16 h) { unsigned u = ((unsigned)h) << 16; return __builtin_bit_cast(float, u); }
DEV unsigned pack2(float a, float b) { return (unsigned)f2bf(a) | ((unsigned)f2bf(b) << 16); }
DEV float sigm(float x) { return 1.f / (1.f + __expf(-x)); }
DEV float ftanh(float x) {
  x = fminf(15.f, fmaxf(-15.f, x));
  float e = __expf(2.f * x);
  return (e - 1.f) / (e + 1.f);
}

// write-through (LLC-visible) stores for cross-XCD intra-kernel dataflow
DEV void st_short_sc(u16* p, u16 v) {
  asm volatile("global_store_short %0, %1, off sc0 sc1" ::"v"(p), "v"((unsigned)v) : "memory");
}
DEV void st_dword_sc(float* p, float v) {
  asm volatile("global_store_dword %0, %1, off sc0 sc1" ::"v"(p), "v"(v) : "memory");
}
DEV void st_dwordu_sc(unsigned* p, unsigned v) {
  asm volatile("global_store_dword %0, %1, off sc0 sc1" ::"v"(p), "v"(v) : "memory");
}
#define VM0 asm volatile("s_waitcnt vmcnt(0)" ::: "memory")

DEV int ld_rel(const int* p) {
  return __hip_atomic_load(p, __ATOMIC_RELAXED, __HIP_MEMORY_SCOPE_AGENT);
}
DEV int ld_acq(const int* p) {
  return __hip_atomic_load(p, __ATOMIC_ACQUIRE, __HIP_MEMORY_SCOPE_AGENT);
}
DEV void ctr_inc(int* p) {
  __hip_atomic_fetch_add(p, 1, __ATOMIC_RELAXED, __HIP_MEMORY_SCOPE_AGENT);
}

// ctrl layout (ints): flags[w] at w*32 (w<32); wh_done at 1024; cvt_done at 1056;
// hmid_done[c] at 1088+32c.
constexpr int CTRL_WH = 1024, CTRL_CVT = 1056, CTRL_HM = 1088;

DEV void cvt_plain_one(const float* __restrict__ in, u16* __restrict__ out, int i) {
  float4 v = reinterpret_cast<const float4*>(in)[i];
  u16x4 o;
  o.x = f2bf(v.x); o.y = f2bf(v.y); o.z = f2bf(v.z); o.w = f2bf(v.w);
  reinterpret_cast<u16x4*>(out)[i] = o;
}
DEV void cvt_split_one(const float* __restrict__ in, u16* __restrict__ hi,
                       u16* __restrict__ lo, int i) {
  float4 v = reinterpret_cast<const float4*>(in)[i];
  u16x4 oh, ol;
  float vv[4] = {v.x, v.y, v.z, v.w};
#pragma unroll
  for (int j = 0; j < 4; ++j) {
    u16 h = f2bf(vv[j]);
    oh[j] = h;
    ol[j] = f2bf(vv[j] - bf2f(h));
  }
  reinterpret_cast<u16x4*>(hi)[i] = oh;
  reinterpret_cast<u16x4*>(lo)[i] = ol;
}

// ---------------- prologue converts: Wih plain + enc split + Whw split ----------------
__global__ void k_cvt_pre(const float* __restrict__ Wih, u16* __restrict__ Wih_bf, int n0,
                          const float* __restrict__ enc, u16* __restrict__ ench,
                          u16* __restrict__ encl, int n1,
                          const float* __restrict__ Whw, u16* __restrict__ whh,
                          u16* __restrict__ whl, int n2) {
  int total = n0 + n1 + n2;
  int i = blockIdx.x * blockDim.x + threadIdx.x;
  int st = gridDim.x * blockDim.x;
  for (; i < total; i += st) {
    if (i < n0) cvt_plain_one(Wih, Wih_bf, i);
    else if (i < n0 + n1) cvt_split_one(enc, ench, encl, i - n0);
    else cvt_split_one(Whw, whh, whl, i - n0 - n1);
  }
}

// embed + pre_h pack + bias sum
__global__ void k_prep(const int* __restrict__ words, const float* __restrict__ emb,
                       u16* __restrict__ xb,
                       const float* __restrict__ pre, unsigned* __restrict__ hp0,
                       const float* __restrict__ bi, const float* __restrict__ bh,
                       float* __restrict__ bsum) {
  int blk = blockIdx.x, tid = threadIdx.x;
  if (blk < Bb * Tt) {
    int row = words[blk];
    int d = tid * 2;
    float2 v = *reinterpret_cast<const float2*>(&emb[(size_t)row * Dd + d]);
    xb[(size_t)blk * Dd + d] = f2bf(v.x);
    xb[(size_t)blk * Dd + d + 1] = f2bf(v.y);
  } else if (blk < Bb * Tt + 32) {
    int i = (blk - Bb * Tt) * 256 + tid;
    float v = pre[i];
    u16 h = f2bf(v);
    u16 l = f2bf(v - bf2f(h));
    hp0[i] = (unsigned)h | ((unsigned)l << 16);
  } else {
    int i = (blk - Bb * Tt - 32) * 256 + tid;
    bsum[i] = bi[i] + bh[i];
  }
}

// ---------------- bf16 GEMM body (prologue xg + wh blocks) ----------------
// CST: 0 = plain f32 C, 2 = write-through f32 C (cross-XCD consumers)
template <bool BIAS, int TERMS, int CST>
DEV void gemm_body(u16* ls, int tile, int tid,
                   const u16* __restrict__ A, const u16* __restrict__ Al,
                   const u16* __restrict__ Bm, const u16* __restrict__ Bl,
                   float* __restrict__ Cf, const float* __restrict__ bias,
                   int M, int N, int K) {
  u16* lsA = ls;
  u16* lsB = ls + 128 * 32;
  u16* lsAl = ls + 2 * 128 * 32;
  u16* lsBl = ls + 3 * 128 * 32;
  const int mt = M >> 7;
  const int tm = (tile % mt) << 7;
  const int tn = (tile / mt) << 7;
  const int wave = tid >> 6, lane = tid & 63;
  const int wr = wave >> 1, wc = wave & 1;
  f32x4 acc[4][4];
#pragma unroll
  for (int i = 0; i < 4; ++i)
#pragma unroll
    for (int j = 0; j < 4; ++j) acc[i][j] = (f32x4){0.f, 0.f, 0.f, 0.f};

  const int lrow = lane >> 2;
  const int lk = (lane & 3) << 3;
  const int fr = lane & 15, fk = (lane >> 4) << 3;

  for (int k0 = 0; k0 < K; k0 += 32) {
#pragma unroll
    for (int r = 0; r < 2; ++r) {
      int rowA = r * 64 + wave * 16;
      size_t goffA = (size_t)(tm + rowA + lrow) * K + k0 + lk;
      size_t goffB = (size_t)(tn + rowA + lrow) * K + k0 + lk;
      __builtin_amdgcn_global_load_lds((const __attribute__((address_space(1))) void*)(A + goffA),
                                       (__attribute__((address_space(3))) void*)&lsA[rowA * 32],
                                       16, 0, 0);
      __builtin_amdgcn_global_load_lds((const __attribute__((address_space(1))) void*)(Bm + goffB),
                                       (__attribute__((address_space(3))) void*)&lsB[rowA * 32],
                                       16, 0, 0);
      if constexpr (TERMS == 3) {
        __builtin_amdgcn_global_load_lds((const __attribute__((address_space(1))) void*)(Al + goffA),
                                         (__attribute__((address_space(3))) void*)&lsAl[rowA * 32],
                                         16, 0, 0);
        __builtin_amdgcn_global_load_lds((const __attribute__((address_space(1))) void*)(Bl + goffB),
                                         (__attribute__((address_space(3))) void*)&lsBl[rowA * 32],
                                         16, 0, 0);
      }
    }
    __syncthreads();
    s16x8 av[4], bv[4];
#pragma unroll
    for (int mi = 0; mi < 4; ++mi)
      av[mi] = *reinterpret_cast<const s16x8*>(&lsA[(wr * 64 + mi * 16 + fr) * 32 + fk]);
#pragma unroll
    for (int ni = 0; ni < 4; ++ni)
      bv[ni] = *reinterpret_cast<const s16x8*>(&lsB[(wc * 64 + ni * 16 + fr) * 32 + fk]);
    if constexpr (TERMS == 3) {
      s16x8 avl[4], bvl[4];
#pragma unroll
      for (int mi = 0; mi < 4; ++mi)
        avl[mi] = *reinterpret_cast<const s16x8*>(&lsAl[(wr * 64 + mi * 16 + fr) * 32 + fk]);
#pragma unroll
      for (int ni = 0; ni < 4; ++ni)
        bvl[ni] = *reinterpret_cast<const s16x8*>(&lsBl[(wc * 64 + ni * 16 + fr) * 32 + fk]);
#pragma unroll
      for (int mi = 0; mi < 4; ++mi)
#pragma unroll
        for (int ni = 0; ni < 4; ++ni) {
          acc[mi][ni] = __builtin_amdgcn_mfma_f32_16x16x32_bf16(av[mi], bv[ni], acc[mi][ni], 0, 0, 0);
          acc[mi][ni] = __builtin_amdgcn_mfma_f32_16x16x32_bf16(av[mi], bvl[ni], acc[mi][ni], 0, 0, 0);
          acc[mi][ni] = __builtin_amdgcn_mfma_f32_16x16x32_bf16(avl[mi], bv[ni], acc[mi][ni], 0, 0, 0);
        }
    } else {
#pragma unroll
      for (int mi = 0; mi < 4; ++mi)
#pragma unroll
        for (int ni = 0; ni < 4; ++ni)
          acc[mi][ni] = __builtin_amdgcn_mfma_f32_16x16x32_bf16(av[mi], bv[ni], acc[mi][ni], 0, 0, 0);
    }
    __syncthreads();
  }

  const int fm = (lane >> 4) << 2;
#pragma unroll
  for (int ni = 0; ni < 4; ++ni) {
    int col = tn + wc * 64 + ni * 16 + fr;
    float badd = 0.f;
    if constexpr (BIAS) badd = bias[col];
#pragma unroll
    for (int mi = 0; mi < 4; ++mi) {
#pragma unroll
      for (int r = 0; r < 4; ++r) {
        int row = tm + wr * 64 + mi * 16 + fm + r;
        size_t idx = (size_t)row * N + col;
        float v = acc[mi][ni][r] + badd;
        if constexpr (CST == 2) st_dword_sc(&Cf[idx], v);
        else Cf[idx] = v;
      }
    }
  }
  if constexpr (CST == 2) VM0;
}

template <bool BIAS, int TERMS>
__global__ __launch_bounds__(256) void k_gemm(const u16* __restrict__ A,
                                              const u16* __restrict__ Al,
                                              const u16* __restrict__ Bm,
                                              const u16* __restrict__ Bl,
                                              float* __restrict__ Cf,
                                              const float* __restrict__ bias,
                                              int M, int N, int K) {
  __shared__ u16 ls[4 * 128 * 32];
  gemm_body<BIAS, TERMS, 0>(ls, blockIdx.x, threadIdx.x, A, Al, Bm, Bl, Cf, bias, M, N, K);
}

// ---------------- LSTM body: R3 barrier protocol (proven, 341us), t-major out -------
DEV void lstm_body(int w, int tid, float* gls,
                   const float* __restrict__ xg, const float* __restrict__ Whh,
                   const float* __restrict__ cell, unsigned* __restrict__ hpack,
                   u16* __restrict__ out_hi, u16* __restrict__ out_lo,
                   int* __restrict__ ctrl) {
  const int gi = tid >> 6, lane = tid & 63;
  const int ds0 = w << 4;
  float (*g_lds)[16][16] = (float(*)[16][16])gls;

  const int fr = lane & 15;
  const int fkb = (lane >> 4) << 3;

  s16x8 whi[16], wlo[16];
  {
    const float* wrow = Whh + (size_t)(gi * Dd + ds0 + fr) * Dd;
#pragma unroll
    for (int kc = 0; kc < 16; ++kc) {
      int k = kc * 32 + fkb;
      float4 a = *reinterpret_cast<const float4*>(&wrow[k]);
      float4 b = *reinterpret_cast<const float4*>(&wrow[k + 4]);
      float vv[8] = {a.x, a.y, a.z, a.w, b.x, b.y, b.z, b.w};
#pragma unroll
      for (int j = 0; j < 8; ++j) {
        u16 h = f2bf(vv[j]);
        whi[kc][j] = (short)h;
        wlo[kc][j] = (short)f2bf(vv[j] - bf2f(h));
      }
    }
  }

  const int ub = tid >> 4, ud = tid & 15;
  float c = cell[(size_t)ub * Dd + ds0 + ud];

  for (int t = 0; t < Tt; ++t) {
    float xgv[4];
#pragma unroll
    for (int r = 0; r < 4; ++r) {
      int bb = ((lane >> 4) << 2) + r;
      xgv[r] = xg[(size_t)(bb * Tt + t) * FD + gi * Dd + ds0 + fr];
    }
#pragma unroll
    for (int r = 0; r < 4; ++r) asm volatile("" ::"v"(xgv[r]));

    if (t > 0) {
      if (gi == 0) {
        if (lane < 32 && lane != w) {
          while (ld_rel(&ctrl[lane * 32]) < t) {}
          while (ld_acq(&ctrl[lane * 32]) < t) {}
        }
        __builtin_amdgcn_sched_barrier(0);
      }
      __syncthreads();
    }

    const unsigned* hp = hpack + (size_t)t * (Bb * Dd) + (size_t)fr * Dd;
    f32x4 a0 = (f32x4){0.f, 0.f, 0.f, 0.f};
    f32x4 a1 = a0, a2 = a0;
#pragma unroll
    for (int kc = 0; kc < 16; ++kc) {
      int k = kc * 32 + fkb;
      u32x4 u0 = *reinterpret_cast<const u32x4*>(&hp[k]);
      u32x4 u1 = *reinterpret_cast<const u32x4*>(&hp[k + 4]);
      s16x8 ahi, alo;
#pragma unroll
      for (int j = 0; j < 4; ++j) {
        ahi[j] = (short)(u0[j] & 0xffffu); alo[j] = (short)(u0[j] >> 16);
        ahi[4 + j] = (short)(u1[j] & 0xffffu); alo[4 + j] = (short)(u1[j] >> 16);
      }
      a0 = __builtin_amdgcn_mfma_f32_16x16x32_bf16(ahi, whi[kc], a0, 0, 0, 0);
      a1 = __builtin_amdgcn_mfma_f32_16x16x32_bf16(ahi, wlo[kc], a1, 0, 0, 0);
      a2 = __builtin_amdgcn_mfma_f32_16x16x32_bf16(alo, whi[kc], a2, 0, 0, 0);
    }
#pragma unroll
    for (int r = 0; r < 4; ++r) {
      int bb = ((lane >> 4) << 2) + r;
      g_lds[gi][bb][fr] = a0[r] + a1[r] + a2[r] + xgv[r];
    }
    __syncthreads();
    float iv = g_lds[0][ub][ud], fv = g_lds[1][ub][ud];
    float gv = g_lds[2][ub][ud], ov = g_lds[3][ub][ud];
    c = sigm(fv) * c + sigm(iv) * ftanh(gv);
    float h = sigm(ov) * ftanh(c);
    u16 hh = f2bf(h);
    u16 hl = f2bf(h - bf2f(hh));
    unsigned pk = (unsigned)hh | ((unsigned)hl << 16);
    __hip_atomic_store(&hpack[(size_t)(t + 1) * (Bb * Dd) + ub * Dd + ds0 + ud], pk,
                       __ATOMIC_RELAXED, __HIP_MEMORY_SCOPE_AGENT);
    // t-major out, write-through (consumed cross-XCD inside this kernel)
    size_t oidx = (size_t)(t * Bb + ub) * Dd + ds0 + ud;
    st_short_sc(&out_hi[oidx], hh);
    st_short_sc(&out_lo[oidx], hl);
    VM0;
    __syncthreads();
    if (tid == 0)
      __hip_atomic_store(&ctrl[w * 32], t + 1, __ATOMIC_RELAXED, __HIP_MEMORY_SCOPE_AGENT);
  }
}

// ---------------- fused tail block: per (chunk c, batch b) — ws -> attn -> V --------
DEV void tail_body(int c, int b, int tid, u16* ls,
                   const u16* __restrict__ out_hi, const u16* __restrict__ out_lo,
                   const u16* __restrict__ Wsw_hi, const u16* __restrict__ Wsw_lo,
                   const float* __restrict__ Ws_b,
                   const float* __restrict__ wh, const float* __restrict__ vt,
                   const float* __restrict__ enc,
                   const u16* __restrict__ Vw_bf, const float* __restrict__ V_b,
                   u16* __restrict__ hmid, int* __restrict__ ctrl) {
  const int wv = tid >> 6, lane = tid & 63;
  const int fr = lane & 15, fkb = (lane >> 4) << 3;
  float (*ws_s)[Dd] = (float(*)[Dd])ls;           // 8x512 f32 = 16KB
  u16 (*cat_s)[2 * Dd] = (u16(*)[2 * Dd])(ls + 8192);  // 8x1024 u16 = 16KB

  // wait: lstm chunk, wh done, cvt done; then one acquire (cache invalidate)
  if (wv == 0) {
    int tgt = (c + 1) * 8;
    if (lane < 32) {
      while (ld_rel(&ctrl[lane * 32]) < tgt) __builtin_amdgcn_s_sleep(2);
    } else if (lane == 32) {
      while (ld_rel(&ctrl[CTRL_WH]) < 64) __builtin_amdgcn_s_sleep(2);
    } else if (lane == 33) {
      while (ld_rel(&ctrl[CTRL_CVT]) < 32) __builtin_amdgcn_s_sleep(2);
    }
    __builtin_amdgcn_sched_barrier(0);
    if (lane == 0) {
      while (ld_acq(&ctrl[CTRL_CVT]) < 32) {}
    }
    __builtin_amdgcn_sched_barrier(0);
  }
  __syncthreads();

  // ---- ws = out @ Ws^T + Ws_b (3-term split), rows = this (c,b)'s 8 t's ----
  {
    f32x4 acc8[8];
#pragma unroll
    for (int n = 0; n < 8; ++n) acc8[n] = (f32x4){0.f, 0.f, 0.f, 0.f};
    const int j = fr & 7;
    const size_t arow = ((size_t)(c * 8 + j) * Bb + b) * Dd;
    for (int kc = 0; kc < 16; ++kc) {
      int k = kc * 32 + fkb;
      s16x8 ah = *reinterpret_cast<const s16x8*>(&out_hi[arow + k]);
      s16x8 al = *reinterpret_cast<const s16x8*>(&out_lo[arow + k]);
#pragma unroll
      for (int n = 0; n < 8; ++n) {
        size_t brow = (size_t)(wv * 128 + n * 16 + fr) * Dd + k;
        s16x8 bh = *reinterpret_cast<const s16x8*>(&Wsw_hi[brow]);
        s16x8 bl = *reinterpret_cast<const s16x8*>(&Wsw_lo[brow]);
        acc8[n] = __builtin_amdgcn_mfma_f32_16x16x32_bf16(ah, bh, acc8[n], 0, 0, 0);
        acc8[n] = __builtin_amdgcn_mfma_f32_16x16x32_bf16(ah, bl, acc8[n], 0, 0, 0);
        acc8[n] = __builtin_amdgcn_mfma_f32_16x16x32_bf16(al, bh, acc8[n], 0, 0, 0);
      }
    }
#pragma unroll
    for (int n = 0; n < 8; ++n) {
      int col = wv * 128 + n * 16 + fr;
      float badd = Ws_b[col];
#pragma unroll
      for (int r = 0; r < 4; ++r) {
        int row = (lane >> 4) * 4 + r;
        if (row < 8) ws_s[row][col] = acc8[n][r] + badd;
      }
    }
  }
  __syncthreads();

  // ---- attention: 2 rows per wave ----
  {
    const int d0 = lane << 3;
    float vtv[8];
    {
      const float4* q = reinterpret_cast<const float4*>(&vt[d0]);
      float4 u = q[0], v = q[1];
      vtv[0] = u.x; vtv[1] = u.y; vtv[2] = u.z; vtv[3] = u.w;
      vtv[4] = v.x; vtv[5] = v.y; vtv[6] = v.z; vtv[7] = v.w;
    }
    for (int rr = 0; rr < 2; ++rr) {
      int j = wv * 2 + rr;
      float wsv[8];
#pragma unroll
      for (int d = 0; d < 8; ++d) wsv[d] = ws_s[j][d0 + d];
      float e0 = 0.f, e1 = 0.f;
      for (int s = 0; s < Ss; ++s) {
        const float4* p = reinterpret_cast<const float4*>(&wh[(size_t)(b * Ss + s) * Dd + d0]);
        float4 x = p[0], y = p[1];
        float whv[8] = {x.x, x.y, x.z, x.w, y.x, y.y, y.z, y.w};
        float a = 0.f;
#pragma unroll
        for (int d = 0; d < 8; ++d) a += ftanh(whv[d] + wsv[d]) * vtv[d];
#pragma unroll
        for (int off = 32; off; off >>= 1) a += __shfl_xor(a, off);
        if (lane == (s & 63)) { if (s < 64) e0 = a; else e1 = a; }
      }
      float m = fmaxf(e0, e1);
#pragma unroll
      for (int off = 32; off; off >>= 1) m = fmaxf(m, __shfl_xor(m, off));
      float p0 = __expf(e0 - m), p1 = __expf(e1 - m);
      float sum = p0 + p1;
#pragma unroll
      for (int off = 32; off; off >>= 1) sum += __shfl_xor(sum, off);
      float inv = 1.f / sum;
      float a0s = p0 * inv, a1s = p1 * inv;
      float ctx[8] = {0.f, 0.f, 0.f, 0.f, 0.f, 0.f, 0.f, 0.f};
      for (int s = 0; s < Ss; ++s) {
        float as = __shfl(s < 64 ? a0s : a1s, s & 63);
        const float4* p = reinterpret_cast<const float4*>(&enc[(size_t)(b * Ss + s) * Dd + d0]);
        float4 x = p[0], y = p[1];
        ctx[0] += as * x.x; ctx[1] += as * x.y; ctx[2] += as * x.z; ctx[3] += as * x.w;
        ctx[4] += as * y.x; ctx[5] += as * y.y; ctx[6] += as * y.z; ctx[7] += as * y.w;
      }
      u16x8 co;
#pragma unroll
      for (int d = 0; d < 8; ++d) co[d] = f2bf(ctx[d]);
      *reinterpret_cast<u16x8*>(&cat_s[j][d0]) = co;
      size_t orow = ((size_t)(c * 8 + j) * Bb + b) * Dd;
      u16x8 ov = *reinterpret_cast<const u16x8*>(&out_hi[orow + d0]);
      *reinterpret_cast<u16x8*>(&cat_s[j][Dd + d0]) = ov;
    }
  }
  __syncthreads();

  // ---- hmid = cat @ V^T + V_b -> bf16 (write-through) ----
  {
    f32x4 acc8[8];
#pragma unroll
    for (int n = 0; n < 8; ++n) acc8[n] = (f32x4){0.f, 0.f, 0.f, 0.f};
    const int j = fr & 7;
    for (int kc = 0; kc < 32; ++kc) {
      int k = kc * 32 + fkb;
      s16x8 a = *reinterpret_cast<const s16x8*>(&cat_s[j][k]);
#pragma unroll
      for (int n = 0; n < 8; ++n) {
        size_t brow = (size_t)(wv * 128 + n * 16 + fr) * (2 * Dd) + k;
        s16x8 bf = *reinterpret_cast<const s16x8*>(&Vw_bf[brow]);
        acc8[n] = __builtin_amdgcn_mfma_f32_16x16x32_bf16(a, bf, acc8[n], 0, 0, 0);
      }
    }
#pragma unroll
    for (int n = 0; n < 8; ++n) {
      int col = wv * 128 + n * 16 + fr;
      float badd = V_b[col];
#pragma unroll
      for (int r = 0; r < 4; ++r) {
        int row = (lane >> 4) * 4 + r;
        if (row < 8) {
          size_t grow = ((size_t)(c * 8 + row) * Bb + b) * Dd + col;
          st_short_sc(&hmid[grow], f2bf(acc8[n][r] + badd));
        }
      }
    }
  }
  VM0;
  __syncthreads();
  if (tid == 0) ctr_inc(&ctrl[CTRL_HM + 32 * c]);
}

// ---------------- logits block: one 128-col Vp panel, loops 8 M-chunks --------------
DEV void logits_body(int n, int tid, u16* ls,
                     const u16* __restrict__ hmid, const u16* __restrict__ Vp_bf,
                     const float* __restrict__ Vp_b, float* __restrict__ out,
                     int* __restrict__ ctrl) {
  u16* lsA = ls;
  u16* lsB = ls + 128 * 32;
  const int wave = tid >> 6, lane = tid & 63;
  const int wr = wave >> 1, wc = wave & 1;
  const int lrow = lane >> 2, lk = (lane & 3) << 3;
  const int fr = lane & 15, fk = (lane >> 4) << 3;
  const int fm = (lane >> 4) << 2;

  // wait converts (Vp ready)
  if (wave == 0) {
    if (lane == 0) {
      while (ld_rel(&ctrl[CTRL_CVT]) < 32) __builtin_amdgcn_s_sleep(2);
      while (ld_acq(&ctrl[CTRL_CVT]) < 32) {}
    }
    __builtin_amdgcn_sched_barrier(0);
  }
  __syncthreads();

  for (int c = 0; c < 8; ++c) {
    if (wave == 0 && lane == 0) {
      while (ld_rel(&ctrl[CTRL_HM + 32 * c]) < 16) __builtin_amdgcn_s_sleep(2);
      while (ld_acq(&ctrl[CTRL_HM + 32 * c]) < 16) {}
    }
    __syncthreads();

    f32x4 acc[4];
#pragma unroll
    for (int i = 0; i < 4; ++i) acc[i] = (f32x4){0.f, 0.f, 0.f, 0.f};
    for (int k0 = 0; k0 < 512; k0 += 32) {
#pragma unroll
      for (int r = 0; r < 2; ++r) {
        int rowA = r * 64 + wave * 16;
        size_t goffA = (size_t)(c * 128 + rowA + lrow) * 512 + k0 + lk;
        size_t goffB = (size_t)(n * 128 + rowA + lrow) * 512 + k0 + lk;
        __builtin_amdgcn_global_load_lds(
            (const __attribute__((address_space(1))) void*)(hmid + goffA),
            (__attribute__((address_space(3))) void*)&lsA[rowA * 32], 16, 0, 0);
        __builtin_amdgcn_global_load_lds(
            (const __attribute__((address_space(1))) void*)(Vp_bf + goffB),
            (__attribute__((address_space(3))) void*)&lsB[rowA * 32], 16, 0, 0);
      }
      __syncthreads();
      s16x8 av[4], bv[4];
#pragma unroll
      for (int mi = 0; mi < 4; ++mi)
        av[mi] = *reinterpret_cast<const s16x8*>(&lsA[(wr * 64 + mi * 16 + fr) * 32 + fk]);
#pragma unroll
      for (int ni = 0; ni < 4; ++ni)
        bv[ni] = *reinterpret_cast<const s16x8*>(&lsB[(wc * 64 + ni * 16 + fr) * 32 + fk]);
      // accumulate into 4x4; reuse acc[mi] per ni via separate regs
#pragma unroll
      for (int mi = 0; mi < 4; ++mi) {
        // acc layout: we need 4x4 frags; pack as accq[mi][ni] in a flat array
      }
      // (flattened below)
      static_assert(true, "");
      // do the 16 MFMAs with a local 4x4 that lives across k0 — see accq
      (void)av; (void)bv;
      // NOTE: replaced by accq version below
      __syncthreads();
      // store frags for this k-step into accq
      // -- this branch never taken; real loop below
      break;
    }
    // ---- real K loop with persistent 4x4 accumulator ----
    f32x4 accq[4][4];
#pragma unroll
    for (int i = 0; i < 4; ++i)
#pragma unroll
      for (int j2 = 0; j2 < 4; ++j2) accq[i][j2] = (f32x4){0.f, 0.f, 0.f, 0.f};
    for (int k0 = 0; k0 < 512; k0 += 32) {
#pragma unroll
      for (int r = 0; r < 2; ++r) {
        int rowA = r * 64 + wave * 16;
        size_t goffA = (size_t)(c * 128 + rowA + lrow) * 512 + k0 + lk;
        size_t goffB = (size_t)(n * 128 + rowA + lrow) * 512 + k0 + lk;
        __builtin_amdgcn_global_load_lds(
            (const __attribute__((address_space(1))) void*)(hmid + goffA),
            (__attribute__((address_space(3))) void*)&lsA[rowA * 32], 16, 0, 0);
        __builtin_amdgcn_global_load_lds(
            (const __attribute__((address_space(1))) void*)(Vp_bf + goffB),
            (__attribute__((address_space(3))) void*)&lsB[rowA * 32], 16, 0, 0);
      }
      __syncthreads();
      s16x8 av[4], bv[4];
#pragma unroll
      for (int mi = 0; mi < 4; ++mi)
        av[mi] = *reinterpret_cast<const s16x8*>(&lsA[(wr * 64 + mi * 16 + fr) * 32 + fk]);
#pragma unroll
      for (int ni = 0; ni < 4; ++ni)
        bv[ni] = *reinterpret_cast<const s16x8*>(&lsB[(wc * 64 + ni * 16 + fr) * 32 + fk]);
#pragma unroll
      for (int mi = 0; mi < 4; ++mi)
#pragma unroll
        for (int ni = 0; ni < 4; ++ni)
          accq[mi][ni] = __builtin_amdgcn_mfma_f32_16x16x32_bf16(av[mi], bv[ni], accq[mi][ni], 0, 0, 0);
      __syncthreads();
    }
#pragma unroll
    for (int ni = 0; ni < 4; ++ni) {
      int col = n * 128 + wc * 64 + ni * 16 + fr;
      float badd = Vp_b[col];
#pragma unroll
      for (int mi = 0; mi < 4; ++mi) {
#pragma unroll
        for (int r = 0; r < 4; ++r) {
          int rowl = wr * 64 + mi * 16 + fm + r;
          int grow = c * 128 + rowl;
          int tt = grow >> 4, bi = grow & 15;
          out[((size_t)bi * Tt + tt) * Vv + col] = accq[mi][ni][r] + badd;
        }
      }
    }
  }
}

// ---------------- mega kernel: role dispatch ----------------
__global__ __launch_bounds__(256) void k_mega(
    const float* __restrict__ xg, const float* __restrict__ Whh,
    const float* __restrict__ cell, unsigned* __restrict__ hpack,
    u16* __restrict__ out_hi, u16* __restrict__ out_lo, int* __restrict__ ctrl,
    const u16* __restrict__ enc_hi, const u16* __restrict__ enc_lo,
    const u16* __restrict__ Whw_hi, const u16* __restrict__ Whw_lo,
    float* __restrict__ wh,
    const float* __restrict__ Vp_w, u16* __restrict__ Vp_bf,
    const float* __restrict__ V_w, u16* __restrict__ Vw_bf,
    const float* __restrict__ Ws_w, u16* __restrict__ Wsw_hi, u16* __restrict__ Wsw_lo,
    const float* __restrict__ Ws_b, const float* __restrict__ vt,
    const float* __restrict__ enc, const float* __restrict__ V_b,
    u16* __restrict__ hmid, const float* __restrict__ Vp_b, float* __restrict__ outp) {
  __shared__ u16 ls[4 * 128 * 32];
  const int blk = blockIdx.x, tid = threadIdx.x;
  if (blk < 32) {
    lstm_body(blk, tid, (float*)ls, xg, Whh, cell, hpack, out_hi, out_lo, ctrl);
  } else if (blk < 96) {
    gemm_body<false, 3, 2>(ls, blk - 32, tid, enc_hi, enc_lo, Whw_hi, Whw_lo,
                           wh, nullptr, 2048, 512, 512);
    __syncthreads();
    if (tid == 0) ctr_inc(&ctrl[CTRL_WH]);
  } else if (blk < 128) {
    // converts: Vp plain, Vw plain, Ws split — as packed write-through pairs
    const int nVpP = Vv * Dd / 2, nVwP = Dd * 2 * Dd / 2, nWsP = Dd * Dd / 2;
    int total = nVpP + nVwP + nWsP;
    int i = (blk - 96) * 256 + tid;
    int st = 32 * 256;
    for (; i < total; i += st) {
      if (i < nVpP) {
        float2 v = reinterpret_cast<const float2*>(Vp_w)[i];
        st_dwordu_sc(&reinterpret_cast<unsigned*>(Vp_bf)[i], pack2(v.x, v.y));
      } else if (i < nVpP + nVwP) {
        int j = i - nVpP;
        float2 v = reinterpret_cast<const float2*>(V_w)[j];
        st_dwordu_sc(&reinterpret_cast<unsigned*>(Vw_bf)[j], pack2(v.x, v.y));
      } else {
        int j = i - nVpP - nVwP;
        float2 v = reinterpret_cast<const float2*>(Ws_w)[j];
        u16 h0 = f2bf(v.x), h1 = f2bf(v.y);
        u16 l0 = f2bf(v.x - bf2f(h0)), l1 = f2bf(v.y - bf2f(h1));
        st_dwordu_sc(&reinterpret_cast<unsigned*>(Wsw_hi)[j], (unsigned)h0 | ((unsigned)h1 << 16));
        st_dwordu_sc(&reinterpret_cast<unsigned*>(Wsw_lo)[j], (unsigned)l0 | ((unsigned)l1 << 16));
      }
    }
    VM0;
    __syncthreads();
    if (tid == 0) ctr_inc(&ctrl[CTRL_CVT]);
  } else if (blk < 256) {
    int c = (blk - 128) >> 4, b = (blk - 128) & 15;
    tail_body(c, b, tid, ls, out_hi, out_lo, Wsw_hi, Wsw_lo, Ws_b, wh, vt, enc,
              Vw_bf, V_b, hmid, ctrl);
  } else {
    logits_body(blk - 256, tid, ls, hmid, Vp_bf, Vp_b, outp, ctrl);
  }
}

// ---------------- host ----------------
extern "C" void kernel_launch(void* const* d_in, const int* in_sizes, int n_in,
                              void* d_out, int out_size, void* d_ws, size_t ws_size,
                              hipStream_t stream) {
  const int* words = (const int*)d_in[0];
  const float* enc = (const float*)d_in[1];
  const float* pre_h = (const float*)d_in[2];
  const float* cell = (const float*)d_in[3];
  const float* emb = (const float*)d_in[4];
  const float* W_ih = (const float*)d_in[5];
  const float* W_hh = (const float*)d_in[6];
  const float* b_ih = (const float*)d_in[7];
  const float* b_hh = (const float*)d_in[8];
  const float* Wh_w = (const float*)d_in[9];
  const float* Ws_w = (const float*)d_in[10];
  const float* Ws_b = (const float*)d_in[11];
  const float* vt_w = (const float*)d_in[12];
  const float* V_w = (const float*)d_in[13];
  const float* V_b = (const float*)d_in[14];
  const float* Vp_w = (const float*)d_in[15];
  const float* Vp_b = (const float*)d_in[16];
  float* outp = (float*)d_out;

  char* ws = (char*)d_ws;
  size_t off = 0;
  auto alloc = [&](size_t bytes) {
    char* p = ws + off;
    off = (off + bytes + 255) & ~(size_t)255;
    return p;
  };
  int* ctrl = (int*)alloc(8192);
  float* xg = (float*)alloc((size_t)Bb * Tt * FD * 4);
  float* wh = (float*)alloc((size_t)Bb * Ss * Dd * 4);
  unsigned* hpack = (unsigned*)alloc((size_t)(Tt + 1) * Bb * Dd * 4);
  u16* out_hi = (u16*)alloc((size_t)Bb * Tt * Dd * 2);
  u16* out_lo = (u16*)alloc((size_t)Bb * Tt * Dd * 2);
  u16* x_bf = (u16*)alloc((size_t)Bb * Tt * Dd * 2);
  u16* enc_hi = (u16*)alloc((size_t)Bb * Ss * Dd * 2);
  u16* enc_lo = (u16*)alloc((size_t)Bb * Ss * Dd * 2);
  u16* Wih_bf = (u16*)alloc((size_t)FD * Dd * 2);
  u16* Whw_hi = (u16*)alloc((size_t)Dd * Dd * 2);
  u16* Whw_lo = (u16*)alloc((size_t)Dd * Dd * 2);
  u16* Wsw_hi = (u16*)alloc((size_t)Dd * Dd * 2);
  u16* Wsw_lo = (u16*)alloc((size_t)Dd * Dd * 2);
  u16* Vw_bf = (u16*)alloc((size_t)Dd * 2 * Dd * 2);
  u16* Vp_bf = (u16*)alloc((size_t)Vv * Dd * 2);
  u16* hmid = (u16*)alloc((size_t)Bb * Tt * Dd * 2);
  float* bsum = (float*)alloc((size_t)FD * 4);
  if (off > ws_size) return;

  hipMemsetAsync(ctrl, 0, 8192, stream);

  k_cvt_pre<<<256, 256, 0, stream>>>(W_ih, Wih_bf, FD * Dd / 4,
                                     enc, enc_hi, enc_lo, Bb * Ss * Dd / 4,
                                     Wh_w, Whw_hi, Whw_lo, Dd * Dd / 4);
  k_prep<<<Bb * Tt + 32 + 8, 256, 0, stream>>>(words, emb, x_bf, pre_h,
                                               (unsigned*)hpack, b_ih, b_hh, bsum);
  // xg = x @ W_ih^T + (b_ih + b_hh)  [1024, 2048]
  k_gemm<true, 1><<<8 * 16, 256, 0, stream>>>(x_bf, nullptr, Wih_bf, nullptr,
                                              xg, bsum, 1024, 2048, 512);
  // mega: LSTM + wh + converts + streamed tail + streamed logits
  k_mega<<<506, 256, 0, stream>>>(xg, W_hh, cell, (unsigned*)hpack, out_hi, out_lo, ctrl,
                                  enc_hi, enc_lo, Whw_hi, Whw_lo, wh,
                                  Vp_w, Vp_bf, V_w, Vw_bf, Ws_w, Wsw_hi, Wsw_lo,
                                  Ws_b, vt_w, enc, V_b, hmid, Vp_b, outp);
}